// Round 1
// baseline (813.299 us; speedup 1.0000x reference)
//
#include <hip/hip_runtime.h>

// RidgeModel: 12 ragged blocks, out[row] = dot(x_row[P], w[P]).
// Row space == flat output space: 384000 rows total.
// Pure HBM-bound: ~1.02 GB read -> floor ~162 us @ 6.3 TB/s.

static constexpr int NBLK = 12;
static constexpr int TOTAL_ROWS = 384000;

struct KArgs {
    const float* x[NBLK];
    const float* w[NBLK];
    float* out;
};

__global__ __launch_bounds__(256) void ridge_dot(KArgs a) {
    // P per block and cumulative row offsets (row = sample*comp index, flat)
    constexpr int P[NBLK] = {128, 256, 512, 1024, 128, 256, 512, 1024, 128, 256, 512, 1024};
    constexpr int ROFF[NBLK + 1] = {0,      8000,   32000,  72000,  128000, 136000,
                                    160000, 200000, 256000, 264000, 288000, 328000,
                                    384000};

    const int lane = threadIdx.x & 63;
    const int wid  = (int)((blockIdx.x * blockDim.x + threadIdx.x) >> 6);
    const int nw   = (int)((gridDim.x * blockDim.x) >> 6);

    for (int row = wid; row < TOTAL_ROWS; row += nw) {
        // wave-uniform block lookup (12-entry unrolled compare)
        int b = 0;
#pragma unroll
        for (int i = 1; i < NBLK; ++i) b += (row >= ROFF[i]) ? 1 : 0;

        const int p   = P[b];
        const int nv  = p >> 2;                 // float4 count per row
        const int rib = row - ROFF[b];          // row within block

        const float4* __restrict__ xr =
            reinterpret_cast<const float4*>(a.x[b]) + (size_t)rib * (size_t)nv;
        const float4* __restrict__ wr = reinterpret_cast<const float4*>(a.w[b]);

        float acc = 0.0f;
        // coalesced: lane l reads float4 at l, l+64, ... (16B/lane)
        for (int j = lane; j < nv; j += 64) {
            const float4 xv = xr[j];
            const float4 wv = wr[j];   // L1-resident (w <= 4 KB per block)
            acc = fmaf(xv.x, wv.x, acc);
            acc = fmaf(xv.y, wv.y, acc);
            acc = fmaf(xv.z, wv.z, acc);
            acc = fmaf(xv.w, wv.w, acc);
        }

        // 64-lane butterfly reduce
#pragma unroll
        for (int off = 32; off > 0; off >>= 1) acc += __shfl_xor(acc, off, 64);

        if (lane == 0) a.out[row] = acc;
    }
}

extern "C" void kernel_launch(void* const* d_in, const int* in_sizes, int n_in,
                              void* d_out, int out_size, void* d_ws, size_t ws_size,
                              hipStream_t stream) {
    (void)n_in; (void)out_size; (void)d_ws; (void)ws_size;

    KArgs a;
    // setup_inputs() dict order is interleaved: x0, w0, x1, w1, ...
    // Defensive: if d_in[1] is NOT a weight (size != 128), assume grouped
    // order x0..x11, w0..w11 instead.
    const bool interleaved = (in_sizes[1] == 128);
    for (int i = 0; i < NBLK; ++i) {
        if (interleaved) {
            a.x[i] = (const float*)d_in[2 * i];
            a.w[i] = (const float*)d_in[2 * i + 1];
        } else {
            a.x[i] = (const float*)d_in[i];
            a.w[i] = (const float*)d_in[NBLK + i];
        }
    }
    a.out = (float*)d_out;

    // 2048 blocks x 256 thr = 8192 waves = full chip residency (256 CU x 32)
    hipLaunchKernelGGL(ridge_dot, dim3(2048), dim3(256), 0, stream, a);
}

// Round 2
// 809.950 us; speedup vs baseline: 1.0041x; 1.0041x over previous
//
#include <hip/hip_runtime.h>

// RidgeModel: 12 ragged blocks, out[row] = dot(x_row[P], w[P]).
// R1 post-mortem: latency-bound (hbm 26%, VALU 22%, occ 89%) — too few
// loads in flight per wave. This version: static wave->block partition,
// w held in registers, specialized per-P paths with 4 independent
// dwordx4 loads in flight per iteration.

static constexpr int NBLK = 12;

struct KArgs {
    const float* x[NBLK];
    const float* w[NBLK];
    float* out;
};

__device__ __forceinline__ float dot4(float4 a, float4 b, float acc) {
    acc = fmaf(a.x, b.x, acc);
    acc = fmaf(a.y, b.y, acc);
    acc = fmaf(a.z, b.z, acc);
    acc = fmaf(a.w, b.w, acc);
    return acc;
}

__device__ __forceinline__ float wave_reduce64(float v) {
#pragma unroll
    for (int off = 32; off > 0; off >>= 1) v += __shfl_xor(v, off, 64);
    return v;
}

// -------- per-P specialized paths (w in VGPRs, multi-load ILP) --------

// P=1024: 1 row/iter, 4 independent 1KB wave-loads in flight. 56000 rows.
__device__ void path1024(const float* __restrict__ xp, const float4* __restrict__ wp,
                         float* __restrict__ outp, int wib, int nw, int lane) {
    const float4 w0 = wp[lane], w1 = wp[lane + 64], w2 = wp[lane + 128], w3 = wp[lane + 192];
    for (int r = wib; r < 56000; r += nw) {
        const float4* __restrict__ xr = (const float4*)xp + (size_t)r * 256;
        float4 a0 = xr[lane];
        float4 a1 = xr[lane + 64];
        float4 a2 = xr[lane + 128];
        float4 a3 = xr[lane + 192];
        float acc = dot4(a0, w0, 0.0f);
        acc = dot4(a1, w1, acc);
        acc = dot4(a2, w2, acc);
        acc = dot4(a3, w3, acc);
        acc = wave_reduce64(acc);
        if (lane == 0) outp[r] = acc;
    }
}

// P=512: 2 rows/iter (4 loads in flight). 40000 rows = 20000 pairs.
__device__ void path512(const float* __restrict__ xp, const float4* __restrict__ wp,
                        float* __restrict__ outp, int wib, int nw, int lane) {
    const float4 w0 = wp[lane], w1 = wp[lane + 64];
    for (int pi = wib; pi < 20000; pi += nw) {
        const int r = 2 * pi;
        const float4* __restrict__ xr = (const float4*)xp + (size_t)r * 128;
        float4 a0 = xr[lane];            // row r
        float4 a1 = xr[lane + 64];
        float4 b0 = xr[lane + 128];      // row r+1
        float4 b1 = xr[lane + 192];
        float sA = dot4(a1, w1, dot4(a0, w0, 0.0f));
        float sB = dot4(b1, w1, dot4(b0, w0, 0.0f));
        sA = wave_reduce64(sA);
        sB = wave_reduce64(sB);
        if (lane == 0) { outp[r] = sA; outp[r + 1] = sB; }
    }
}

// P=256: 4 contiguous rows/iter = one 4KB coalesced span. 24000 rows = 6000 quads.
__device__ void path256(const float* __restrict__ xp, const float4* __restrict__ wp,
                        float* __restrict__ outp, int wib, int nw, int lane) {
    const float4 w0 = wp[lane];
    for (int qi = wib; qi < 6000; qi += nw) {
        const int r = 4 * qi;
        const float4* __restrict__ xr = (const float4*)xp + (size_t)r * 64;
        float4 a0 = xr[lane];
        float4 a1 = xr[lane + 64];
        float4 a2 = xr[lane + 128];
        float4 a3 = xr[lane + 192];
        float s0 = dot4(a0, w0, 0.0f);
        float s1 = dot4(a1, w0, 0.0f);
        float s2 = dot4(a2, w0, 0.0f);
        float s3 = dot4(a3, w0, 0.0f);
        s0 = wave_reduce64(s0);
        s1 = wave_reduce64(s1);
        s2 = wave_reduce64(s2);
        s3 = wave_reduce64(s3);
        if (lane == 0) { outp[r] = s0; outp[r + 1] = s1; outp[r + 2] = s2; outp[r + 3] = s3; }
    }
}

// P=128: half-wave per row (32 lanes x 32 float4), 8 rows/iter. 8000 rows = 1000 octets.
__device__ void path128(const float* __restrict__ xp, const float4* __restrict__ wp,
                        float* __restrict__ outp, int wib, int nw, int lane) {
    const int half = lane >> 5;   // 0: even row of pair, 1: odd row
    const int l32  = lane & 31;
    const float4 w0 = wp[l32];
    for (int oi = wib; oi < 1000; oi += nw) {
        const float4* __restrict__ xr = (const float4*)xp + (size_t)oi * 256; // 8 rows x 32 f4
        float4 a0 = xr[lane];            // rows 8oi+0 / 8oi+1
        float4 a1 = xr[lane + 64];       // rows 8oi+2 / 8oi+3
        float4 a2 = xr[lane + 128];      // rows 8oi+4 / 8oi+5
        float4 a3 = xr[lane + 192];      // rows 8oi+6 / 8oi+7
        float s0 = dot4(a0, w0, 0.0f);
        float s1 = dot4(a1, w0, 0.0f);
        float s2 = dot4(a2, w0, 0.0f);
        float s3 = dot4(a3, w0, 0.0f);
        // reduce within each 32-lane half (offsets < 32 stay in-half)
#pragma unroll
        for (int off = 16; off > 0; off >>= 1) {
            s0 += __shfl_xor(s0, off, 64);
            s1 += __shfl_xor(s1, off, 64);
            s2 += __shfl_xor(s2, off, 64);
            s3 += __shfl_xor(s3, off, 64);
        }
        if (l32 == 0) {
            const int r = 8 * oi + half;
            outp[r]     = s0;
            outp[r + 2] = s1;
            outp[r + 4] = s2;
            outp[r + 6] = s3;
        }
    }
}

// ---------------- dispatcher ----------------

__global__ __launch_bounds__(256) void ridge_dot(KArgs a) {
    // waves per block instance, proportional to bytes; totals exactly 8192
    constexpr int WOFF[NBLK + 1] = {0,    32,   232,  888,  2731, 2763, 2963,
                                    3619, 5462, 5494, 5694, 6350, 8192};
    constexpr int WCNT[NBLK] = {32, 200, 656, 1843, 32, 200, 656, 1843, 32, 200, 656, 1842};
    constexpr int ROFF[NBLK] = {0,      8000,   32000,  72000,  128000, 136000,
                                160000, 200000, 256000, 264000, 288000, 328000};

    const int lane = threadIdx.x & 63;
    const int wid  = (int)((blockIdx.x * blockDim.x + threadIdx.x) >> 6);

    int b = 0;
#pragma unroll
    for (int i = 1; i < NBLK; ++i) b += (wid >= WOFF[i]) ? 1 : 0;

    const int wib = wid - WOFF[b];
    const int nw  = WCNT[b];
    const float* __restrict__  xp = a.x[b];
    const float4* __restrict__ wp = (const float4*)a.w[b];
    float* __restrict__ outp = a.out + ROFF[b];

    switch (b & 3) {
        case 0: path128 (xp, wp, outp, wib, nw, lane); break;
        case 1: path256 (xp, wp, outp, wib, nw, lane); break;
        case 2: path512 (xp, wp, outp, wib, nw, lane); break;
        default: path1024(xp, wp, outp, wib, nw, lane); break;
    }
}

extern "C" void kernel_launch(void* const* d_in, const int* in_sizes, int n_in,
                              void* d_out, int out_size, void* d_ws, size_t ws_size,
                              hipStream_t stream) {
    (void)n_in; (void)out_size; (void)d_ws; (void)ws_size;

    KArgs a;
    // setup_inputs() dict order is interleaved: x0, w0, x1, w1, ...
    const bool interleaved = (in_sizes[1] == 128);
    for (int i = 0; i < NBLK; ++i) {
        if (interleaved) {
            a.x[i] = (const float*)d_in[2 * i];
            a.w[i] = (const float*)d_in[2 * i + 1];
        } else {
            a.x[i] = (const float*)d_in[i];
            a.w[i] = (const float*)d_in[NBLK + i];
        }
    }
    a.out = (float*)d_out;

    // 2048 blocks x 256 thr = 8192 waves = exactly 32 waves/CU on 256 CUs
    hipLaunchKernelGGL(ridge_dot, dim3(2048), dim3(256), 0, stream, a);
}